// Round 1
// baseline (2127.571 us; speedup 1.0000x reference)
//
#include <hip/hip_runtime.h>
#include <stdint.h>

#define K_DIM 4096
#define N_DIM 16384
#define M_DIM 8192

typedef _Float16 half8 __attribute__((ext_vector_type(8)));
typedef float floatx4 __attribute__((ext_vector_type(4)));

// async 16B global -> LDS (direct DMA, no VGPR round trip)
__device__ inline void gld_lds16(const void* g, void* l) {
  __builtin_amdgcn_global_load_lds(
      (const __attribute__((address_space(1))) void*)g,
      (__attribute__((address_space(3))) void*)l, 16, 0, 0);
}

// ---- pre-pass converters: fp32 -> f16, int32 -> f16 (8 elems/thread) ----
__global__ __launch_bounds__(256) void cvt_f32_f16_k(const float* __restrict__ in,
                                                     _Float16* __restrict__ out) {
  size_t idx = (size_t)blockIdx.x * 256 + threadIdx.x;
  const float4* p = (const float4*)in + idx * 2;
  float4 v0 = p[0], v1 = p[1];
  half8 h;
  h[0] = (_Float16)v0.x; h[1] = (_Float16)v0.y; h[2] = (_Float16)v0.z; h[3] = (_Float16)v0.w;
  h[4] = (_Float16)v1.x; h[5] = (_Float16)v1.y; h[6] = (_Float16)v1.z; h[7] = (_Float16)v1.w;
  *((half8*)out + idx) = h;
}

__global__ __launch_bounds__(256) void cvt_i32_f16_k(const int* __restrict__ in,
                                                     _Float16* __restrict__ out) {
  size_t idx = (size_t)blockIdx.x * 256 + threadIdx.x;
  const int4* p = (const int4*)in + idx * 2;
  int4 v0 = p[0], v1 = p[1];
  half8 h;
  h[0] = (_Float16)v0.x; h[1] = (_Float16)v0.y; h[2] = (_Float16)v0.z; h[3] = (_Float16)v0.w;
  h[4] = (_Float16)v1.x; h[5] = (_Float16)v1.y; h[6] = (_Float16)v1.z; h[7] = (_Float16)v1.w;
  *((half8*)out + idx) = h;
}

// ---- main GEMM: C[m,n] = sum_k A[m,k]*B[n,k]  (both K-contiguous, "BT" form)
// 128x128 tile, BK=64, 256 threads = 4 waves (2x2), wave does 64x64 via
// 4x4 grid of mfma_f32_16x16x32_f16. LDS layout is XOR-swizzled at 16B
// granules: granule (row r, slot sc) holds logical k-chunk (sc ^ (r&7)).
// Staging permutes the GLOBAL source address per lane (global_load_lds
// forces lane-linear LDS destinations), fragment reads apply the same XOR
// -> ds_read_b128 bank conflicts drop from 16-way to 2-way (free, m136).
template <bool FROM_WS>
__global__ __launch_bounds__(256) void qgemm_k(const void* __restrict__ Av,
                                               const void* __restrict__ Bv,
                                               const float* __restrict__ scale_p,
                                               const float* __restrict__ bias,
                                               float* __restrict__ out) {
  constexpr int BK = 64;
  __shared__ __align__(16) _Float16 sA[128 * BK];  // 16 KB
  __shared__ __align__(16) _Float16 sB[128 * BK];  // 16 KB

  const int tid  = threadIdx.x;
  const int lane = tid & 63;
  const int wid  = tid >> 6;
  const int wm   = wid >> 1, wn = wid & 1;
  const int q    = lane >> 4;
  const int l15  = lane & 15;
  const int bn   = blockIdx.x, bm = blockIdx.y;

  // staging granules: tile = 128 rows x 8 granules(16B) = 1024; 4 per thread
  int gI[4], rI[4], cI[4];
#pragma unroll
  for (int p = 0; p < 4; ++p) {
    int g = p * 256 + tid;
    gI[p] = g;
    rI[p] = g >> 3;                      // row within tile
    cI[p] = (g & 7) ^ (rI[p] & 7);       // logical k-chunk stored at this slot
  }

  floatx4 acc[4][4] = {};

  const int arow = wm * 64 + l15;        // fragment row bases (add i*16)
  const int brow = wn * 64 + l15;

  const _Float16* Ah = nullptr; const _Float16* Bh = nullptr;
  const float* Af = nullptr;    const int* Bq = nullptr;
  if constexpr (FROM_WS) { Ah = (const _Float16*)Av; Bh = (const _Float16*)Bv; }
  else                   { Af = (const float*)Av;    Bq = (const int*)Bv; }

#pragma unroll 1
  for (int k0 = 0; k0 < K_DIM; k0 += BK) {
    if constexpr (FROM_WS) {
#pragma unroll
      for (int p = 0; p < 4; ++p)
        gld_lds16(Ah + (size_t)(bm * 128 + rI[p]) * K_DIM + k0 + cI[p] * 8,
                  &sA[gI[p] * 8]);
#pragma unroll
      for (int p = 0; p < 4; ++p)
        gld_lds16(Bh + (size_t)(bn * 128 + rI[p]) * K_DIM + k0 + cI[p] * 8,
                  &sB[gI[p] * 8]);
    } else {
#pragma unroll
      for (int p = 0; p < 4; ++p) {
        const float4* pa =
            (const float4*)(Af + (size_t)(bm * 128 + rI[p]) * K_DIM + k0 + cI[p] * 8);
        float4 v0 = pa[0], v1 = pa[1];
        half8 h;
        h[0] = (_Float16)v0.x; h[1] = (_Float16)v0.y; h[2] = (_Float16)v0.z; h[3] = (_Float16)v0.w;
        h[4] = (_Float16)v1.x; h[5] = (_Float16)v1.y; h[6] = (_Float16)v1.z; h[7] = (_Float16)v1.w;
        *(half8*)&sA[gI[p] * 8] = h;
      }
#pragma unroll
      for (int p = 0; p < 4; ++p) {
        const int4* pb =
            (const int4*)(Bq + (size_t)(bn * 128 + rI[p]) * K_DIM + k0 + cI[p] * 8);
        int4 v0 = pb[0], v1 = pb[1];
        half8 h;
        h[0] = (_Float16)v0.x; h[1] = (_Float16)v0.y; h[2] = (_Float16)v0.z; h[3] = (_Float16)v0.w;
        h[4] = (_Float16)v1.x; h[5] = (_Float16)v1.y; h[6] = (_Float16)v1.z; h[7] = (_Float16)v1.w;
        *(half8*)&sB[gI[p] * 8] = h;
      }
    }
    __syncthreads();

#pragma unroll
    for (int kk = 0; kk < BK; kk += 32) {
      const int xt = ((((kk >> 3) + q) ^ (lane & 7)) * 8);  // swizzled k-offset (halves)
      half8 af[4], bf[4];
#pragma unroll
      for (int i = 0; i < 4; ++i) af[i] = *(const half8*)&sA[(arow + i * 16) * BK + xt];
#pragma unroll
      for (int j = 0; j < 4; ++j) bf[j] = *(const half8*)&sB[(brow + j * 16) * BK + xt];
#pragma unroll
      for (int i = 0; i < 4; ++i)
#pragma unroll
        for (int j = 0; j < 4; ++j)
          acc[i][j] = __builtin_amdgcn_mfma_f32_16x16x32_f16(af[i], bf[j], acc[i][j], 0, 0, 0);
    }
    __syncthreads();
  }

  // epilogue: out = acc*scale + bias   (C/D layout: col=lane&15, row=q*4+reg)
  const float s = *scale_p;
  float bv[4];
#pragma unroll
  for (int j = 0; j < 4; ++j) bv[j] = bias[bn * 128 + wn * 64 + j * 16 + l15];
  const int mb = bm * 128 + wm * 64 + q * 4;
  const size_t nb = (size_t)bn * 128 + wn * 64 + l15;
#pragma unroll
  for (int i = 0; i < 4; ++i) {
#pragma unroll
    for (int j = 0; j < 4; ++j) {
      size_t off = (size_t)(mb + i * 16) * N_DIM + nb + j * 16;
      floatx4 c = acc[i][j];
      out[off]             = c[0] * s + bv[j];
      out[off + N_DIM]     = c[1] * s + bv[j];
      out[off + 2 * N_DIM] = c[2] * s + bv[j];
      out[off + 3 * N_DIM] = c[3] * s + bv[j];
    }
  }
}

extern "C" void kernel_launch(void* const* d_in, const int* in_sizes, int n_in,
                              void* d_out, int out_size, void* d_ws, size_t ws_size,
                              hipStream_t stream) {
  const float* x     = (const float*)d_in[0];
  const int*   qw    = (const int*)d_in[1];
  const float* scale = (const float*)d_in[2];
  const float* bias  = (const float*)d_in[3];
  float* out = (float*)d_out;

  const size_t xs  = (size_t)M_DIM * K_DIM;   // 33.5M elems
  const size_t wsz = (size_t)N_DIM * K_DIM;   // 67.1M elems
  const size_t need = (xs + wsz) * sizeof(_Float16);  // 192 MB

  dim3 grid(N_DIM / 128, M_DIM / 128);
  if (ws_size >= need) {
    _Float16* xh = (_Float16*)d_ws;
    _Float16* wh = xh + xs;
    cvt_f32_f16_k<<<(int)(xs / 8 / 256), 256, 0, stream>>>(x, xh);
    cvt_i32_f16_k<<<(int)(wsz / 8 / 256), 256, 0, stream>>>(qw, wh);
    qgemm_k<true><<<grid, 256, 0, stream>>>(xh, wh, scale, bias, out);
  } else {
    qgemm_k<false><<<grid, 256, 0, stream>>>(x, qw, scale, bias, out);
  }
}